// Round 1
// baseline (125.254 us; speedup 1.0000x reference)
//
#include <hip/hip_runtime.h>
#include <math.h>

#define L 2048
#define B 4
#define QH 32
#define KVH 8
#define G 4
#define D 128
#define NS (B*KVH)   /* 32 kv streams */
#define WS 12
#define MASK_CONST -50000.0f
#define EPS_F 1.1920929e-07f

// dec[t,n] = keys[t,n,D-1] > 2.0 ? 1 : 0
// wts[t,n] = sigmoid(mean_g(queries[t,b,h*G+g,D-1]) + 2.0) + EPS
__global__ void prep_kernel(const float* __restrict__ q, const float* __restrict__ k,
                            float* __restrict__ dec, float* __restrict__ wts) {
    int idx = blockIdx.x * blockDim.x + threadIdx.x;
    if (idx >= L * NS) return;
    int n = idx & (NS - 1);
    int t = idx / NS;
    float kv = k[(size_t)idx * D + (D - 1)];
    dec[idx] = (kv > 2.0f) ? 1.0f : 0.0f;
    int b = n >> 3, h = n & 7;
    const float* qb = q + (((size_t)t * B + b) * QH + h * G) * D + (D - 1);
    float s = qb[0] + qb[D] + qb[2 * D] + qb[3 * D];
    float logit = s * 0.25f + 2.0f;
    wts[idx] = 1.0f / (1.0f + expf(-logit)) + EPS_F;
}

// q_out: copy queries, zero channel D-1
__global__ void qcopy_kernel(const float4* __restrict__ q, float4* __restrict__ out) {
    size_t i = (size_t)blockIdx.x * blockDim.x + threadIdx.x;
    if (i >= (size_t)L * B * QH * (D / 4)) return;
    float4 v = q[i];
    if ((i & (D / 4 - 1)) == (D / 4 - 1)) v.w = 0.0f;
    out[i] = v;
}

// mask[t,b,qh] = (t<L-1) ? dec[t+1, b*8+qh/4] * MASK_CONST : 0
__global__ void mask_kernel(const float* __restrict__ dec, float* __restrict__ mask) {
    int idx = blockIdx.x * blockDim.x + threadIdx.x;
    if (idx >= L * B * QH) return;
    int qh = idx & (QH - 1);
    int b = (idx >> 5) & (B - 1);
    int t = idx >> 7;
    float m = 0.0f;
    if (t < L - 1) m = dec[(t + 1) * NS + b * KVH + (qh >> 2)] * MASK_CONST;
    mask[idx] = m;
}

// One 64-lane wave per (t,n): 64 lanes x float4 = 256 channels (k|v concat).
// pooled[t] = sum_{s in trailing accepted run, s>=t-11, s>=0} w[s]*x[s] / sum w[s]
// Writes 4 GQA head copies each for k2 (ch127 zeroed) and v2.
__global__ void pool_kernel(const float* __restrict__ k, const float* __restrict__ v,
                            const float* __restrict__ dec, const float* __restrict__ wts,
                            float* __restrict__ k2, float* __restrict__ v2) {
    int grp  = threadIdx.x >> 6;           // 0..3 waves per block
    int lane = threadIdx.x & 63;
    int pair = blockIdx.x * 4 + grp;       // (t,n) index, 0..65535
    int n = pair & (NS - 1);
    int t = pair / NS;
    int c = lane * 4;                      // channel base in concat [0,256)
    const bool is_k = (c < D);
    const float* base = is_k ? k : v;
    int coff = is_k ? c : (c - D);

    float ax = 0.f, ay = 0.f, az = 0.f, aw = 0.f, den = 0.f;
    float g = 1.f;
    for (int j = 0; j < WS; ++j) {
        int s = t - j;
        if (s < 0) break;
        if (j > 0) {                       // gate: product of dec over (s, t]
            g *= dec[(s + 1) * NS + n];
            if (g == 0.f) break;           // wave-uniform break
        }
        float w = wts[s * NS + n];
        const float4 x = *reinterpret_cast<const float4*>(base + ((size_t)s * NS + n) * D + coff);
        ax += w * x.x; ay += w * x.y; az += w * x.z; aw += w * x.w;
        den += w;
    }
    float4 o;
    o.x = ax / den; o.y = ay / den; o.z = az / den; o.w = aw / den;

    int b = n >> 3, h = n & 7;
    size_t head0 = (((size_t)t * B + b) * QH + h * G) * D;   // first of 4 heads
    if (is_k) {
        if (c == D - 4) o.w = 0.0f;        // zero pooled-k channel 127
        float4* dst = reinterpret_cast<float4*>(k2) + (head0 + c) / 4;
        dst[0] = o; dst[D / 4] = o; dst[2 * (D / 4)] = o; dst[3 * (D / 4)] = o;
    } else {
        float4* dst = reinterpret_cast<float4*>(v2) + (head0 + (c - D)) / 4;
        dst[0] = o; dst[D / 4] = o; dst[2 * (D / 4)] = o; dst[3 * (D / 4)] = o;
    }
}

extern "C" void kernel_launch(void* const* d_in, const int* in_sizes, int n_in,
                              void* d_out, int out_size, void* d_ws, size_t ws_size,
                              hipStream_t stream) {
    const float* q = (const float*)d_in[0];   // (L,B,QH,D)
    const float* k = (const float*)d_in[1];   // (L,B,KVH,D)
    const float* v = (const float*)d_in[2];   // (L,B,KVH,D)

    float* out_q    = (float*)d_out;                          // 33,554,432
    float* out_k2   = out_q  + (size_t)L * B * QH * D;        // 33,554,432
    float* out_v2   = out_k2 + (size_t)L * B * QH * D;        // 33,554,432
    float* out_mask = out_v2 + (size_t)L * B * QH * D;        // 262,144

    float* dec = (float*)d_ws;            // L*NS floats
    float* wts = dec + (size_t)L * NS;    // L*NS floats

    // prep: dec + weights
    {
        int total = L * NS;                       // 65536
        prep_kernel<<<(total + 255) / 256, 256, 0, stream>>>(q, k, dec, wts);
    }
    // q copy (float4)
    {
        size_t total = (size_t)L * B * QH * (D / 4);  // 8,388,608
        qcopy_kernel<<<(int)((total + 255) / 256), 256, 0, stream>>>(
            (const float4*)q, (float4*)out_q);
    }
    // pooling + GQA-expanded k2/v2
    {
        int blocks = (L * NS) / 4;                // 16384 blocks, 4 waves each
        pool_kernel<<<blocks, 256, 0, stream>>>(k, v, dec, wts, out_k2, out_v2);
    }
    // mask
    {
        int total = L * B * QH;                   // 262,144
        mask_kernel<<<(total + 255) / 256, 256, 0, stream>>>(dec, out_mask);
    }
}

// Round 3
// 100.393 us; speedup vs baseline: 1.2476x; 1.2476x over previous
//
#include <hip/hip_runtime.h>
#include <math.h>

#define L 2048
#define B 4
#define QH 32
#define KVH 8
#define G 4
#define D 128
#define NS (B*KVH)   /* 32 kv streams */
#define WS 12
#define MASK_CONST -50000.0f
#define EPS_F 1.1920929e-07f

#define NQ_BLOCKS   32768   /* L*B*QH*D/4 float4 / 256 threads */
#define NPOOL_BLOCKS 16384  /* L*NS pairs / 4 waves per block */
#define NMASK_BLOCKS 1024   /* L*B*QH / 256 */

typedef float f32x4 __attribute__((ext_vector_type(4)));

// dec[t,n] = keys[t,n,D-1] > 2.0 ? 1 : 0
// wts[t,n] = sigmoid(mean_g(queries[t,b,h*G+g,D-1]) + 2.0) + EPS
__global__ void prep_kernel(const float* __restrict__ q, const float* __restrict__ k,
                            float* __restrict__ dec, float* __restrict__ wts) {
    int idx = blockIdx.x * blockDim.x + threadIdx.x;
    if (idx >= L * NS) return;
    int n = idx & (NS - 1);
    int t = idx / NS;
    float kv = k[(size_t)idx * D + (D - 1)];
    dec[idx] = (kv > 2.0f) ? 1.0f : 0.0f;
    int b = n >> 3, h = n & 7;
    const float* qb = q + (((size_t)t * B + b) * QH + h * G) * D + (D - 1);
    float s = qb[0] + qb[D] + qb[2 * D] + qb[3 * D];
    float logit = s * 0.25f + 2.0f;
    wts[idx] = 1.0f / (1.0f + expf(-logit)) + EPS_F;
}

// Fused: qcopy (blocks [0,NQ)), pool (blocks [NQ,NQ+NPOOL)), mask (rest).
__global__ void fused_kernel(const f32x4* __restrict__ q4,
                             const float* __restrict__ k, const float* __restrict__ v,
                             const float* __restrict__ dec, const float* __restrict__ wts,
                             f32x4* __restrict__ outq4,
                             float* __restrict__ k2, float* __restrict__ v2,
                             float* __restrict__ mask) {
    int bid = blockIdx.x;
    if (bid < NQ_BLOCKS) {
        // ---- q copy, zero channel D-1, streaming (nontemporal) ----
        size_t i = (size_t)bid * 256 + threadIdx.x;
        f32x4 val = __builtin_nontemporal_load(&q4[i]);
        if ((i & (D / 4 - 1)) == (D / 4 - 1)) val.w = 0.0f;
        __builtin_nontemporal_store(val, &outq4[i]);
    } else if (bid < NQ_BLOCKS + NPOOL_BLOCKS) {
        // ---- pooling + GQA-expanded k2/v2 ----
        int pb   = bid - NQ_BLOCKS;
        int grp  = threadIdx.x >> 6;           // 4 waves per block
        int lane = threadIdx.x & 63;
        int pair = pb * 4 + grp;               // (t,n) index
        int n = pair & (NS - 1);
        int t = pair / NS;
        int c = lane * 4;                      // channel in concat [0,256)
        const bool is_k = (c < D);
        const float* base = is_k ? k : v;
        int coff = is_k ? c : (c - D);

        float ax = 0.f, ay = 0.f, az = 0.f, aw = 0.f, den = 0.f;
        float g = 1.f;
        for (int j = 0; j < WS; ++j) {
            int s = t - j;
            if (s < 0) break;
            if (j > 0) {                       // gate: product of dec over (s, t]
                g *= dec[(s + 1) * NS + n];
                if (g == 0.f) break;           // wave-uniform break
            }
            float w = wts[s * NS + n];
            const f32x4 x = *reinterpret_cast<const f32x4*>(base + ((size_t)s * NS + n) * D + coff);
            ax += w * x.x; ay += w * x.y; az += w * x.z; aw += w * x.w;
            den += w;
        }
        f32x4 o;
        o.x = ax / den; o.y = ay / den; o.z = az / den; o.w = aw / den;

        int b = n >> 3, h = n & 7;
        size_t head0 = (((size_t)t * B + b) * QH + h * G) * D;   // first of 4 GQA heads
        if (is_k) {
            if (c == D - 4) o.w = 0.0f;        // zero pooled-k channel 127
            f32x4* dst = reinterpret_cast<f32x4*>(k2) + (head0 + c) / 4;
            __builtin_nontemporal_store(o, dst);
            __builtin_nontemporal_store(o, dst + D / 4);
            __builtin_nontemporal_store(o, dst + 2 * (D / 4));
            __builtin_nontemporal_store(o, dst + 3 * (D / 4));
        } else {
            f32x4* dst = reinterpret_cast<f32x4*>(v2) + (head0 + (c - D)) / 4;
            __builtin_nontemporal_store(o, dst);
            __builtin_nontemporal_store(o, dst + D / 4);
            __builtin_nontemporal_store(o, dst + 2 * (D / 4));
            __builtin_nontemporal_store(o, dst + 3 * (D / 4));
        }
    } else {
        // ---- mask ----
        int idx = (bid - NQ_BLOCKS - NPOOL_BLOCKS) * 256 + threadIdx.x;
        int qh = idx & (QH - 1);
        int b = (idx >> 5) & (B - 1);
        int t = idx >> 7;
        float m = 0.0f;
        if (t < L - 1) m = dec[(t + 1) * NS + b * KVH + (qh >> 2)] * MASK_CONST;
        mask[idx] = m;
    }
}

extern "C" void kernel_launch(void* const* d_in, const int* in_sizes, int n_in,
                              void* d_out, int out_size, void* d_ws, size_t ws_size,
                              hipStream_t stream) {
    const float* q = (const float*)d_in[0];   // (L,B,QH,D)
    const float* k = (const float*)d_in[1];   // (L,B,KVH,D)
    const float* v = (const float*)d_in[2];   // (L,B,KVH,D)

    float* out_q    = (float*)d_out;                          // 33,554,432
    float* out_k2   = out_q  + (size_t)L * B * QH * D;        // 33,554,432
    float* out_v2   = out_k2 + (size_t)L * B * QH * D;        // 33,554,432
    float* out_mask = out_v2 + (size_t)L * B * QH * D;        // 262,144

    float* dec = (float*)d_ws;            // L*NS floats
    float* wts = dec + (size_t)L * NS;    // L*NS floats

    {
        int total = L * NS;                       // 65536
        prep_kernel<<<(total + 255) / 256, 256, 0, stream>>>(q, k, dec, wts);
    }
    {
        int blocks = NQ_BLOCKS + NPOOL_BLOCKS + NMASK_BLOCKS;  // 50176
        fused_kernel<<<blocks, 256, 0, stream>>>(
            (const f32x4*)q, k, v, dec, wts,
            (f32x4*)out_q, out_k2, out_v2, out_mask);
    }
}